// Round 1
// baseline (6006.164 us; speedup 1.0000x reference)
//
#include <hip/hip_runtime.h>

#define D 128
#define TN 64
#define KT 32

// ---------------- CSR build ----------------

__global__ void count_edges(const int* __restrict__ dst, int E, int* __restrict__ cnt) {
    int e = blockIdx.x * blockDim.x + threadIdx.x;
    if (e < E) atomicAdd(&cnt[dst[e]], 1);
}

// single-block scan over n counts -> exclusive offsets, cursor copy, 1/max(cnt,1)
__global__ void scan_offsets(const int* __restrict__ cnt, int n,
                             int* __restrict__ row_off, int* __restrict__ cur,
                             float* __restrict__ inv_cnt) {
    __shared__ int sums[1024];
    int tid = threadIdx.x;
    int chunk = (n + 1023) / 1024;
    int lo = tid * chunk;
    int hi = min(lo + chunk, n);
    int s = 0;
    for (int i = lo; i < hi; ++i) s += cnt[i];
    sums[tid] = s;
    __syncthreads();
    for (int off = 1; off < 1024; off <<= 1) {
        int v = (tid >= off) ? sums[tid - off] : 0;
        __syncthreads();
        sums[tid] += v;
        __syncthreads();
    }
    int run = (tid == 0) ? 0 : sums[tid - 1];
    for (int i = lo; i < hi; ++i) {
        row_off[i] = run;
        cur[i] = run;
        int c = cnt[i];
        inv_cnt[i] = 1.0f / (float)max(c, 1);
        run += c;
    }
    if (lo < n && hi == n) row_off[n] = run;
}

__global__ void fill_csr(const int* __restrict__ src, const int* __restrict__ dst, int E,
                         int* __restrict__ cur, int* __restrict__ csr_src) {
    int e = blockIdx.x * blockDim.x + threadIdx.x;
    if (e < E) {
        int d = dst[e];
        int pos = atomicAdd(&cur[d], 1);
        csr_src[pos] = src[e];
    }
}

// ---------------- mean aggregation: one block (128 thr) per node ----------------

__global__ void aggregate(const float* __restrict__ x, const int* __restrict__ csr_src,
                          const int* __restrict__ row_off, const float* __restrict__ inv_cnt,
                          float* __restrict__ mean_out) {
    int i = blockIdx.x;
    int t = threadIdx.x;
    int lo = row_off[i], hi = row_off[i + 1];
    float acc = 0.f;
    for (int e = lo; e < hi; ++e) {
        int s = csr_src[e];
        acc += x[(size_t)s * D + t];
    }
    mean_out[(size_t)i * D + t] = acc * inv_cnt[i];
}

// ---------------- fused SAGE linear: out = mean@Wl^T + x@Wr^T + b (opt. relu) ----
// GEMM view: A = [mean | x]  (n x 256),  B = [Wl | Wr] (128 x 256), C = n x 128.
// Tile: 64 nodes x 128 outs, 256 threads, each thread 4 nodes x 8 outs.

template <int RELU>
__global__ void sage_gemm(const float* __restrict__ mean, const float* __restrict__ xin,
                          const float* __restrict__ Wl, const float* __restrict__ Wr,
                          const float* __restrict__ bias, float* __restrict__ out, int n) {
    __shared__ float As[TN][KT + 1];   // 64 x 33
    __shared__ float Bs[D][KT + 1];    // 128 x 33
    int tid = threadIdx.x;
    int node0 = blockIdx.x * TN;
    int gn = tid >> 4;   // 0..15 : node group
    int go = tid & 15;   // 0..15 : out group

    float acc[4][8];
#pragma unroll
    for (int i = 0; i < 4; ++i)
#pragma unroll
        for (int j = 0; j < 8; ++j) acc[i][j] = 0.f;

#pragma unroll
    for (int kt = 0; kt < 8; ++kt) {
        int k0 = kt * KT;                     // 0..224 over concat K=256
        const float* Asrc = (k0 < D) ? mean : xin;
        const float* Bsrc = (k0 < D) ? Wl : Wr;
        int ka = (k0 < D) ? k0 : (k0 - D);

        __syncthreads();
        {
            int col = tid & 31;
            int rbase = tid >> 5;             // 0..7
#pragma unroll
            for (int r = 0; r < 8; ++r) {     // A: 64x32
                int row = rbase + r * 8;
                int node = node0 + row;
                float v = 0.f;
                if (node < n) v = Asrc[(size_t)node * D + ka + col];
                As[row][col] = v;
            }
#pragma unroll
            for (int r = 0; r < 16; ++r) {    // B: 128x32
                int row = rbase + r * 8;
                Bs[row][col] = Bsrc[row * D + ka + col];
            }
        }
        __syncthreads();

#pragma unroll
        for (int kk = 0; kk < KT; ++kk) {
            float a[4], b[8];
#pragma unroll
            for (int i = 0; i < 4; ++i) a[i] = As[gn + i * 16][kk];   // broadcast reads
#pragma unroll
            for (int j = 0; j < 8; ++j) b[j] = Bs[go + j * 16][kk];   // 16 rows, stride 33 -> conflict-free
#pragma unroll
            for (int i = 0; i < 4; ++i)
#pragma unroll
                for (int j = 0; j < 8; ++j) acc[i][j] += a[i] * b[j];
        }
    }

#pragma unroll
    for (int i = 0; i < 4; ++i) {
        int node = node0 + gn + i * 16;
        if (node >= n) continue;
#pragma unroll
        for (int j = 0; j < 8; ++j) {
            int o = go + j * 16;
            float v = acc[i][j] + bias[o];
            if (RELU) v = fmaxf(v, 0.f);
            out[(size_t)node * D + o] = v;    // coalesced per j
        }
    }
}

// ---------------- launch ----------------

extern "C" void kernel_launch(void* const* d_in, const int* in_sizes, int n_in,
                              void* d_out, int out_size, void* d_ws, size_t ws_size,
                              hipStream_t stream) {
    const float* x  = (const float*)d_in[0];
    const int* edge = (const int*)d_in[1];
    const float* W1l = (const float*)d_in[2];
    const float* b1  = (const float*)d_in[3];
    const float* W1r = (const float*)d_in[4];
    const float* W2l = (const float*)d_in[5];
    const float* b2  = (const float*)d_in[6];
    const float* W2r = (const float*)d_in[7];
    float* out = (float*)d_out;

    int n = in_sizes[0] / D;       // 50000
    int E = in_sizes[1] / 2;       // 625000
    const int* src = edge;
    const int* dst = edge + E;

    char* w = (char*)d_ws;
    auto alloc = [&](size_t bytes) {
        char* p = w;
        w += (bytes + 255) & ~(size_t)255;
        return p;
    };
    int* cnt      = (int*)alloc((size_t)n * 4);
    int* row_off  = (int*)alloc((size_t)(n + 1) * 4);
    int* cur      = (int*)alloc((size_t)n * 4);
    float* invc   = (float*)alloc((size_t)n * 4);
    int* csr_src  = (int*)alloc((size_t)E * 4);
    float* meanb  = (float*)alloc((size_t)n * D * 4);
    float* hbuf   = (float*)alloc((size_t)n * D * 4);

    hipMemsetAsync(cnt, 0, (size_t)n * 4, stream);
    count_edges<<<(E + 255) / 256, 256, 0, stream>>>(dst, E, cnt);
    scan_offsets<<<1, 1024, 0, stream>>>(cnt, n, row_off, cur, invc);
    fill_csr<<<(E + 255) / 256, 256, 0, stream>>>(src, dst, E, cur, csr_src);

    int gemm_blocks = (n + TN - 1) / TN;

    // layer 1
    aggregate<<<n, D, 0, stream>>>(x, csr_src, row_off, invc, meanb);
    sage_gemm<1><<<gemm_blocks, 256, 0, stream>>>(meanb, x, W1l, W1r, b1, hbuf, n);
    // layer 2
    aggregate<<<n, D, 0, stream>>>(hbuf, csr_src, row_off, invc, meanb);
    sage_gemm<0><<<gemm_blocks, 256, 0, stream>>>(meanb, hbuf, W2l, W2r, b2, out, n);
}

// Round 2
// 5627.634 us; speedup vs baseline: 1.0673x; 1.0673x over previous
//
#include <hip/hip_runtime.h>

#define D 128
#define TN 64
#define KT 32
#define PAD 36   // LDS row stride in floats: 16B-aligned for float4, <=2-way bank conflict on reads

// ---------------- CSR build ----------------

__global__ void count_edges(const int* __restrict__ dst, int E, int* __restrict__ cnt) {
    int e = blockIdx.x * blockDim.x + threadIdx.x;
    if (e < E) atomicAdd(&cnt[dst[e]], 1);
}

// single-block scan over n counts -> exclusive offsets, cursor copy, 1/max(cnt,1)
__global__ void scan_offsets(const int* __restrict__ cnt, int n,
                             int* __restrict__ row_off, int* __restrict__ cur,
                             float* __restrict__ inv_cnt) {
    __shared__ int sums[1024];
    int tid = threadIdx.x;
    int chunk = (n + 1023) / 1024;
    int lo = tid * chunk;
    int hi = min(lo + chunk, n);
    int s = 0;
    for (int i = lo; i < hi; ++i) s += cnt[i];
    sums[tid] = s;
    __syncthreads();
    for (int off = 1; off < 1024; off <<= 1) {
        int v = (tid >= off) ? sums[tid - off] : 0;
        __syncthreads();
        sums[tid] += v;
        __syncthreads();
    }
    int run = (tid == 0) ? 0 : sums[tid - 1];
    for (int i = lo; i < hi; ++i) {
        row_off[i] = run;
        cur[i] = run;
        int c = cnt[i];
        inv_cnt[i] = 1.0f / (float)max(c, 1);
        run += c;
    }
    if (lo < n && hi == n) row_off[n] = run;
}

__global__ void fill_csr(const int* __restrict__ src, const int* __restrict__ dst, int E,
                         int* __restrict__ cur, int* __restrict__ csr_src) {
    int e = blockIdx.x * blockDim.x + threadIdx.x;
    if (e < E) {
        int d = dst[e];
        int pos = atomicAdd(&cur[d], 1);
        csr_src[pos] = src[e];
    }
}

// ---------------- mean aggregation: one block (128 thr) per node ----------------

__global__ void aggregate(const float* __restrict__ x, const int* __restrict__ csr_src,
                          const int* __restrict__ row_off, const float* __restrict__ inv_cnt,
                          float* __restrict__ mean_out) {
    int i = blockIdx.x;
    int t = threadIdx.x;
    int lo = row_off[i], hi = row_off[i + 1];
    float acc = 0.f;
    for (int e = lo; e < hi; ++e) {
        int s = csr_src[e];
        acc += x[(size_t)s * D + t];
    }
    mean_out[(size_t)i * D + t] = acc * inv_cnt[i];
}

// ---------------- fused SAGE linear: out = mean@Wl^T + x@Wr^T + b (opt. relu) ----
// GEMM view: A = [mean | x]  (n x 256),  B = [Wl | Wr] (128 x 256), C = n x 128.
// Tile: 64 nodes x 128 outs, 256 threads, each thread 4 nodes x 8 outs.
// __launch_bounds__(256,2): VGPR cap 256 -> acc[4][8] stays in registers (r0 spilled at 64-cap).

template <int RELU>
__global__ __launch_bounds__(256, 2)
void sage_gemm(const float* __restrict__ mean, const float* __restrict__ xin,
               const float* __restrict__ Wl, const float* __restrict__ Wr,
               const float* __restrict__ bias, float* __restrict__ out, int n) {
    __shared__ float As[TN][PAD];   // 64 x 36
    __shared__ float Bs[D][PAD];    // 128 x 36
    int tid = threadIdx.x;
    int node0 = blockIdx.x * TN;
    int gn = tid >> 4;   // 0..15 : node group
    int go = tid & 15;   // 0..15 : out group

    float acc[4][8];
#pragma unroll
    for (int i = 0; i < 4; ++i)
#pragma unroll
        for (int j = 0; j < 8; ++j) acc[i][j] = 0.f;

    int r4 = tid >> 3;          // 0..31
    int c4 = (tid & 7) * 4;     // 0,4,...,28

#pragma unroll
    for (int kt = 0; kt < 8; ++kt) {
        int k0 = kt * KT;                     // 0..224 over concat K=256
        const float* Asrc = (k0 < D) ? mean : xin;
        const float* Bsrc = (k0 < D) ? Wl : Wr;
        int ka = (k0 < D) ? k0 : (k0 - D);

        __syncthreads();
        // A: 64x32, float4 per thread x2
#pragma unroll
        for (int rr = 0; rr < 2; ++rr) {
            int row = r4 + rr * 32;
            int node = node0 + row;
            float4 v = make_float4(0.f, 0.f, 0.f, 0.f);
            if (node < n) v = *(const float4*)&Asrc[(size_t)node * D + ka + c4];
            *(float4*)&As[row][c4] = v;
        }
        // B: 128x32, float4 per thread x4
#pragma unroll
        for (int rr = 0; rr < 4; ++rr) {
            int row = r4 + rr * 32;
            *(float4*)&Bs[row][c4] = *(const float4*)&Bsrc[row * D + ka + c4];
        }
        __syncthreads();

#pragma unroll
        for (int kk = 0; kk < KT; ++kk) {
            float a[4], b[8];
#pragma unroll
            for (int i = 0; i < 4; ++i) a[i] = As[gn + i * 16][kk];   // broadcast reads
#pragma unroll
            for (int j = 0; j < 8; ++j) b[j] = Bs[go + j * 16][kk];   // 2-way max -> free
#pragma unroll
            for (int i = 0; i < 4; ++i)
#pragma unroll
                for (int j = 0; j < 8; ++j) acc[i][j] += a[i] * b[j];
        }
    }

#pragma unroll
    for (int i = 0; i < 4; ++i) {
        int node = node0 + gn + i * 16;
        if (node >= n) continue;
#pragma unroll
        for (int j = 0; j < 8; ++j) {
            int o = go + j * 16;
            float v = acc[i][j] + bias[o];
            if (RELU) v = fmaxf(v, 0.f);
            out[(size_t)node * D + o] = v;    // coalesced per j
        }
    }
}

// ---------------- launch ----------------

extern "C" void kernel_launch(void* const* d_in, const int* in_sizes, int n_in,
                              void* d_out, int out_size, void* d_ws, size_t ws_size,
                              hipStream_t stream) {
    const float* x  = (const float*)d_in[0];
    const int* edge = (const int*)d_in[1];
    const float* W1l = (const float*)d_in[2];
    const float* b1  = (const float*)d_in[3];
    const float* W1r = (const float*)d_in[4];
    const float* W2l = (const float*)d_in[5];
    const float* b2  = (const float*)d_in[6];
    const float* W2r = (const float*)d_in[7];
    float* out = (float*)d_out;

    int n = in_sizes[0] / D;       // 50000
    int E = in_sizes[1] / 2;       // 625000
    const int* src = edge;
    const int* dst = edge + E;

    char* w = (char*)d_ws;
    auto alloc = [&](size_t bytes) {
        char* p = w;
        w += (bytes + 255) & ~(size_t)255;
        return p;
    };
    int* cnt      = (int*)alloc((size_t)n * 4);
    int* row_off  = (int*)alloc((size_t)(n + 1) * 4);
    int* cur      = (int*)alloc((size_t)n * 4);
    float* invc   = (float*)alloc((size_t)n * 4);
    int* csr_src  = (int*)alloc((size_t)E * 4);
    float* meanb  = (float*)alloc((size_t)n * D * 4);
    float* hbuf   = (float*)alloc((size_t)n * D * 4);

    hipMemsetAsync(cnt, 0, (size_t)n * 4, stream);
    count_edges<<<(E + 255) / 256, 256, 0, stream>>>(dst, E, cnt);
    scan_offsets<<<1, 1024, 0, stream>>>(cnt, n, row_off, cur, invc);
    fill_csr<<<(E + 255) / 256, 256, 0, stream>>>(src, dst, E, cur, csr_src);

    int gemm_blocks = (n + TN - 1) / TN;

    // layer 1
    aggregate<<<n, D, 0, stream>>>(x, csr_src, row_off, invc, meanb);
    sage_gemm<1><<<gemm_blocks, 256, 0, stream>>>(meanb, x, W1l, W1r, b1, hbuf, n);
    // layer 2
    aggregate<<<n, D, 0, stream>>>(hbuf, csr_src, row_off, invc, meanb);
    sage_gemm<0><<<gemm_blocks, 256, 0, stream>>>(meanb, hbuf, W2l, W2r, b2, out, n);
}

// Round 3
// 572.651 us; speedup vs baseline: 10.4883x; 9.8273x over previous
//
#include <hip/hip_runtime.h>

#define D 128
#define TN 64
#define KT 32
#define PAD 37   // ODD row stride: A-reads (rows 16 apart) -> 2-way bank alias (free);
                 // B-reads (16 distinct rows) conflict-free. Staging uses scalar ds_writes.

// ---------------- CSR build ----------------

__global__ void count_edges(const int* __restrict__ dst, int E, int* __restrict__ cnt) {
    int e = blockIdx.x * blockDim.x + threadIdx.x;
    if (e < E) atomicAdd(&cnt[dst[e]], 1);
}

__global__ void scan_offsets(const int* __restrict__ cnt, int n,
                             int* __restrict__ row_off, int* __restrict__ cur,
                             float* __restrict__ inv_cnt) {
    __shared__ int sums[1024];
    int tid = threadIdx.x;
    int chunk = (n + 1023) / 1024;
    int lo = tid * chunk;
    int hi = min(lo + chunk, n);
    int s = 0;
    for (int i = lo; i < hi; ++i) s += cnt[i];
    sums[tid] = s;
    __syncthreads();
    for (int off = 1; off < 1024; off <<= 1) {
        int v = (tid >= off) ? sums[tid - off] : 0;
        __syncthreads();
        sums[tid] += v;
        __syncthreads();
    }
    int run = (tid == 0) ? 0 : sums[tid - 1];
    for (int i = lo; i < hi; ++i) {
        row_off[i] = run;
        cur[i] = run;
        int c = cnt[i];
        inv_cnt[i] = 1.0f / (float)max(c, 1);
        run += c;
    }
    if (lo < n && hi == n) row_off[n] = run;
}

__global__ void fill_csr(const int* __restrict__ src, const int* __restrict__ dst, int E,
                         int* __restrict__ cur, int* __restrict__ csr_src) {
    int e = blockIdx.x * blockDim.x + threadIdx.x;
    if (e < E) {
        int d = dst[e];
        int pos = atomicAdd(&cur[d], 1);
        csr_src[pos] = src[e];
    }
}

// ---------------- mean aggregation: one WAVE per node, grid-stride ----------------

__global__ __launch_bounds__(256)
void aggregate(const float* __restrict__ x, const int* __restrict__ csr_src,
               const int* __restrict__ row_off, const float* __restrict__ inv_cnt,
               float* __restrict__ mean_out, int n) {
    int wave  = (blockIdx.x * blockDim.x + threadIdx.x) >> 6;
    int lane  = threadIdx.x & 63;
    int nwave = (gridDim.x * blockDim.x) >> 6;
    for (int i = wave; i < n; i += nwave) {
        int lo = row_off[i], hi = row_off[i + 1];
        float ax = 0.f, ay = 0.f;
        for (int e = lo; e < hi; ++e) {
            int s = __builtin_amdgcn_readfirstlane(csr_src[e]);   // wave-uniform -> SGPR
            float2 v = *(const float2*)&x[(size_t)s * D + lane * 2];
            ax += v.x; ay += v.y;
        }
        float ic = inv_cnt[i];
        *(float2*)&mean_out[(size_t)i * D + lane * 2] = make_float2(ax * ic, ay * ic);
    }
}

// ---------------- fused SAGE linear: out = mean@Wl^T + x@Wr^T + b (opt. relu) ----
// GEMM view: A = [mean | x] (n x 256), B = [Wl | Wr] (128 x 256), C = n x 128.
// Tile: 64 nodes x 128 outs, 256 threads, thread = 4 nodes x 8 outs.
// kt loop NOT unrolled (unroll 1): prevents cross-phase software-pipelining of the
// 6 float4 staging temps x 8 phases that (theory) spilled to scratch in r1/r2.

template <int RELU>
__global__ __launch_bounds__(256, 2)
void sage_gemm(const float* __restrict__ mean, const float* __restrict__ xin,
               const float* __restrict__ Wl, const float* __restrict__ Wr,
               const float* __restrict__ bias, float* __restrict__ out, int n) {
    __shared__ float As[TN][PAD];
    __shared__ float Bs[D][PAD];
    const int tid = threadIdx.x;
    const int node0 = blockIdx.x * TN;
    const int gn = tid >> 4;   // 0..15 node group
    const int go = tid & 15;   // 0..15 out group
    const int r4 = tid >> 3;        // 0..31
    const int c4 = (tid & 7) * 4;   // 0,4,..,28

    float acc[4][8];
#pragma unroll
    for (int i = 0; i < 4; ++i)
#pragma unroll
        for (int j = 0; j < 8; ++j) acc[i][j] = 0.f;

#pragma unroll 1
    for (int kt = 0; kt < 8; ++kt) {
        const int k0 = kt * KT;
        const float* __restrict__ Asrc = (k0 < D) ? mean : xin;
        const float* __restrict__ Bsrc = (k0 < D) ? Wl : Wr;
        const int ka = k0 & (D - 1);

        // phase 1: global -> regs (exactly this phase's loads, nothing more)
        float4 av[2], bv[4];
#pragma unroll
        for (int rr = 0; rr < 2; ++rr) {
            int node = node0 + r4 + rr * 32;
            av[rr] = make_float4(0.f, 0.f, 0.f, 0.f);
            if (node < n) av[rr] = *(const float4*)&Asrc[(size_t)node * D + ka + c4];
        }
#pragma unroll
        for (int rr = 0; rr < 4; ++rr)
            bv[rr] = *(const float4*)&Bsrc[(r4 + rr * 32) * D + ka + c4];

        __syncthreads();
        // phase 2: regs -> LDS (scalar writes; PAD=37 rows are not 16B-aligned)
#pragma unroll
        for (int rr = 0; rr < 2; ++rr) {
            int row = r4 + rr * 32;
            As[row][c4 + 0] = av[rr].x;
            As[row][c4 + 1] = av[rr].y;
            As[row][c4 + 2] = av[rr].z;
            As[row][c4 + 3] = av[rr].w;
        }
#pragma unroll
        for (int rr = 0; rr < 4; ++rr) {
            int row = r4 + rr * 32;
            Bs[row][c4 + 0] = bv[rr].x;
            Bs[row][c4 + 1] = bv[rr].y;
            Bs[row][c4 + 2] = bv[rr].z;
            Bs[row][c4 + 3] = bv[rr].w;
        }
        __syncthreads();

        // phase 3: FMA inner loop, float2 LDS reads (8B aligned: PAD odd * even kk... rows*37*4
        // byte base; kk even -> offset 8B-aligned only when (row*37+kk) even; use scalar-safe float2
        // via two b32 when misaligned -- simplest: read as two floats, compiler fuses to ds_read2)
#pragma unroll
        for (int kk = 0; kk < KT; kk += 2) {
            float a0[4], a1[4], b0[8], b1[8];
#pragma unroll
            for (int i = 0; i < 4; ++i) {
                a0[i] = As[gn + i * 16][kk];
                a1[i] = As[gn + i * 16][kk + 1];
            }
#pragma unroll
            for (int j = 0; j < 8; ++j) {
                b0[j] = Bs[go + j * 16][kk];
                b1[j] = Bs[go + j * 16][kk + 1];
            }
#pragma unroll
            for (int i = 0; i < 4; ++i)
#pragma unroll
                for (int j = 0; j < 8; ++j)
                    acc[i][j] += a0[i] * b0[j] + a1[i] * b1[j];
        }
    }

#pragma unroll
    for (int i = 0; i < 4; ++i) {
        int node = node0 + gn + i * 16;
        if (node >= n) continue;
#pragma unroll
        for (int j = 0; j < 8; ++j) {
            int o = go + j * 16;
            float v = acc[i][j] + bias[o];
            if (RELU) v = fmaxf(v, 0.f);
            out[(size_t)node * D + o] = v;
        }
    }
}

// ---------------- launch ----------------

extern "C" void kernel_launch(void* const* d_in, const int* in_sizes, int n_in,
                              void* d_out, int out_size, void* d_ws, size_t ws_size,
                              hipStream_t stream) {
    const float* x  = (const float*)d_in[0];
    const int* edge = (const int*)d_in[1];
    const float* W1l = (const float*)d_in[2];
    const float* b1  = (const float*)d_in[3];
    const float* W1r = (const float*)d_in[4];
    const float* W2l = (const float*)d_in[5];
    const float* b2  = (const float*)d_in[6];
    const float* W2r = (const float*)d_in[7];
    float* out = (float*)d_out;

    int n = in_sizes[0] / D;       // 50000
    int E = in_sizes[1] / 2;       // 625000
    const int* src = edge;
    const int* dst = edge + E;

    char* w = (char*)d_ws;
    auto alloc = [&](size_t bytes) {
        char* p = w;
        w += (bytes + 255) & ~(size_t)255;
        return p;
    };
    int* cnt      = (int*)alloc((size_t)n * 4);
    int* row_off  = (int*)alloc((size_t)(n + 1) * 4);
    int* cur      = (int*)alloc((size_t)n * 4);
    float* invc   = (float*)alloc((size_t)n * 4);
    int* csr_src  = (int*)alloc((size_t)E * 4);
    float* meanb  = (float*)alloc((size_t)n * D * 4);
    float* hbuf   = (float*)alloc((size_t)n * D * 4);

    hipMemsetAsync(cnt, 0, (size_t)n * 4, stream);
    count_edges<<<(E + 255) / 256, 256, 0, stream>>>(dst, E, cnt);
    scan_offsets<<<1, 1024, 0, stream>>>(cnt, n, row_off, cur, invc);
    fill_csr<<<(E + 255) / 256, 256, 0, stream>>>(src, dst, E, cur, csr_src);

    int gemm_blocks = (n + TN - 1) / TN;
    int agg_blocks = 2048;

    // layer 1
    aggregate<<<agg_blocks, 256, 0, stream>>>(x, csr_src, row_off, invc, meanb, n);
    sage_gemm<1><<<gemm_blocks, 256, 0, stream>>>(meanb, x, W1l, W1r, b1, hbuf, n);
    // layer 2
    aggregate<<<agg_blocks, 256, 0, stream>>>(hbuf, csr_src, row_off, invc, meanb, n);
    sage_gemm<0><<<gemm_blocks, 256, 0, stream>>>(meanb, hbuf, W2l, W2r, b2, out, n);
}

// Round 4
// 413.629 us; speedup vs baseline: 14.5207x; 1.3845x over previous
//
#include <hip/hip_runtime.h>

#define D 128
#define TN 64
#define KT 32
#define PAD 37   // ODD row stride: A-reads (rows 16 apart) -> 2-way bank alias (free);
                 // B-reads (16 distinct rows) conflict-free. Staging uses scalar ds_writes.
#define SCAN_B 256

// ---------------- CSR build ----------------

__global__ void count_edges(const int* __restrict__ dst, int E, int* __restrict__ cnt) {
    int e = blockIdx.x * blockDim.x + threadIdx.x;
    if (e < E) atomicAdd(&cnt[dst[e]], 1);
}

// hierarchical exclusive scan over cnt[n]:
// s1: per-block sums; s2: single-block scan of block sums; s3: final offsets.

__global__ void scan_part(const int* __restrict__ cnt, int n, int* __restrict__ blk_sum) {
    __shared__ int s[SCAN_B];
    int i = blockIdx.x * SCAN_B + threadIdx.x;
    s[threadIdx.x] = (i < n) ? cnt[i] : 0;
    __syncthreads();
#pragma unroll
    for (int off = SCAN_B / 2; off > 0; off >>= 1) {
        if (threadIdx.x < off) s[threadIdx.x] += s[threadIdx.x + off];
        __syncthreads();
    }
    if (threadIdx.x == 0) blk_sum[blockIdx.x] = s[0];
}

__global__ void scan_top(int* __restrict__ blk_sum, int nb) {
    __shared__ int s[1024];
    int t = threadIdx.x;
    int v = (t < nb) ? blk_sum[t] : 0;
    s[t] = v;
    __syncthreads();
    for (int off = 1; off < 1024; off <<= 1) {
        int u = (t >= off) ? s[t - off] : 0;
        __syncthreads();
        s[t] += u;
        __syncthreads();
    }
    if (t < nb) blk_sum[t] = s[t] - v;   // exclusive
}

__global__ void scan_final(const int* __restrict__ cnt, int n, const int* __restrict__ blk_sum,
                           int* __restrict__ row_off, int* __restrict__ cur,
                           float* __restrict__ inv_cnt) {
    __shared__ int s[SCAN_B];
    int i = blockIdx.x * SCAN_B + threadIdx.x;
    int v = (i < n) ? cnt[i] : 0;
    s[threadIdx.x] = v;
    __syncthreads();
    for (int off = 1; off < SCAN_B; off <<= 1) {
        int u = (threadIdx.x >= off) ? s[threadIdx.x - off] : 0;
        __syncthreads();
        s[threadIdx.x] += u;
        __syncthreads();
    }
    if (i < n) {
        int excl = blk_sum[blockIdx.x] + s[threadIdx.x] - v;   // exclusive prefix
        row_off[i] = excl;
        cur[i] = excl;
        inv_cnt[i] = 1.0f / (float)max(v, 1);
        if (i == n - 1) row_off[n] = excl + v;
    }
}

__global__ void fill_csr(const int* __restrict__ src, const int* __restrict__ dst, int E,
                         int* __restrict__ cur, int* __restrict__ csr_src) {
    int e = blockIdx.x * blockDim.x + threadIdx.x;
    if (e < E) {
        int d = dst[e];
        int pos = atomicAdd(&cur[d], 1);
        csr_src[pos] = src[e];
    }
}

// ---------------- mean aggregation: 2 nodes per wave (one per 32-lane half) ----------
// Each half gathers its node's neighbor rows with float4/lane (32 lanes x 16B = 512B row).

__global__ __launch_bounds__(256)
void aggregate(const float* __restrict__ x, const int* __restrict__ csr_src,
               const int* __restrict__ row_off, const float* __restrict__ inv_cnt,
               float* __restrict__ mean_out, int n) {
    int wave  = (blockIdx.x * blockDim.x + threadIdx.x) >> 6;
    int lane  = threadIdx.x & 63;
    int half  = lane >> 5;
    int l32   = lane & 31;
    int nwave = (gridDim.x * blockDim.x) >> 6;
    for (int p = wave; 2 * p < n; p += nwave) {
        int i = 2 * p + half;
        if (i >= n) continue;
        int lo = row_off[i], hi = row_off[i + 1];
        float4 a = make_float4(0.f, 0.f, 0.f, 0.f);
        for (int e = lo; e < hi; ++e) {
            int s = csr_src[e];                                    // broadcast within half
            float4 v = *(const float4*)&x[(size_t)s * D + l32 * 4];
            a.x += v.x; a.y += v.y; a.z += v.z; a.w += v.w;
        }
        float ic = inv_cnt[i];
        a.x *= ic; a.y *= ic; a.z *= ic; a.w *= ic;
        *(float4*)&mean_out[(size_t)i * D + l32 * 4] = a;
    }
}

// ---------------- fused SAGE linear: out = mean@Wl^T + x@Wr^T + b (opt. relu) ----
// GEMM view: A = [mean | x] (n x 256), B = [Wl | Wr] (128 x 256), C = n x 128.
// Tile: 64 nodes x 128 outs, 256 threads, thread = 4 nodes x 8 outs.
// kt loop NOT unrolled (unroll 1): prevents cross-phase software-pipelining of the
// staging temps that caused GB-scale scratch spill traffic in r1/r2.

template <int RELU>
__global__ __launch_bounds__(256, 2)
void sage_gemm(const float* __restrict__ mean, const float* __restrict__ xin,
               const float* __restrict__ Wl, const float* __restrict__ Wr,
               const float* __restrict__ bias, float* __restrict__ out, int n) {
    __shared__ float As[TN][PAD];
    __shared__ float Bs[D][PAD];
    const int tid = threadIdx.x;
    const int node0 = blockIdx.x * TN;
    const int gn = tid >> 4;   // 0..15 node group
    const int go = tid & 15;   // 0..15 out group
    const int r4 = tid >> 3;        // 0..31
    const int c4 = (tid & 7) * 4;   // 0,4,..,28

    float acc[4][8];
#pragma unroll
    for (int i = 0; i < 4; ++i)
#pragma unroll
        for (int j = 0; j < 8; ++j) acc[i][j] = 0.f;

#pragma unroll 1
    for (int kt = 0; kt < 8; ++kt) {
        const int k0 = kt * KT;
        const float* __restrict__ Asrc = (k0 < D) ? mean : xin;
        const float* __restrict__ Bsrc = (k0 < D) ? Wl : Wr;
        const int ka = k0 & (D - 1);

        // phase 1: global -> regs
        float4 av[2], bv[4];
#pragma unroll
        for (int rr = 0; rr < 2; ++rr) {
            int node = node0 + r4 + rr * 32;
            av[rr] = make_float4(0.f, 0.f, 0.f, 0.f);
            if (node < n) av[rr] = *(const float4*)&Asrc[(size_t)node * D + ka + c4];
        }
#pragma unroll
        for (int rr = 0; rr < 4; ++rr)
            bv[rr] = *(const float4*)&Bsrc[(r4 + rr * 32) * D + ka + c4];

        __syncthreads();
        // phase 2: regs -> LDS
#pragma unroll
        for (int rr = 0; rr < 2; ++rr) {
            int row = r4 + rr * 32;
            As[row][c4 + 0] = av[rr].x;
            As[row][c4 + 1] = av[rr].y;
            As[row][c4 + 2] = av[rr].z;
            As[row][c4 + 3] = av[rr].w;
        }
#pragma unroll
        for (int rr = 0; rr < 4; ++rr) {
            int row = r4 + rr * 32;
            Bs[row][c4 + 0] = bv[rr].x;
            Bs[row][c4 + 1] = bv[rr].y;
            Bs[row][c4 + 2] = bv[rr].z;
            Bs[row][c4 + 3] = bv[rr].w;
        }
        __syncthreads();

        // phase 3: FMA inner loop
#pragma unroll
        for (int kk = 0; kk < KT; kk += 2) {
            float a0[4], a1[4], b0[8], b1[8];
#pragma unroll
            for (int i = 0; i < 4; ++i) {
                a0[i] = As[gn + i * 16][kk];
                a1[i] = As[gn + i * 16][kk + 1];
            }
#pragma unroll
            for (int j = 0; j < 8; ++j) {
                b0[j] = Bs[go + j * 16][kk];
                b1[j] = Bs[go + j * 16][kk + 1];
            }
#pragma unroll
            for (int i = 0; i < 4; ++i)
#pragma unroll
                for (int j = 0; j < 8; ++j)
                    acc[i][j] += a0[i] * b0[j] + a1[i] * b1[j];
        }
    }

#pragma unroll
    for (int i = 0; i < 4; ++i) {
        int node = node0 + gn + i * 16;
        if (node >= n) continue;
#pragma unroll
        for (int j = 0; j < 8; ++j) {
            int o = go + j * 16;
            float v = acc[i][j] + bias[o];
            if (RELU) v = fmaxf(v, 0.f);
            out[(size_t)node * D + o] = v;
        }
    }
}

// ---------------- launch ----------------

extern "C" void kernel_launch(void* const* d_in, const int* in_sizes, int n_in,
                              void* d_out, int out_size, void* d_ws, size_t ws_size,
                              hipStream_t stream) {
    const float* x  = (const float*)d_in[0];
    const int* edge = (const int*)d_in[1];
    const float* W1l = (const float*)d_in[2];
    const float* b1  = (const float*)d_in[3];
    const float* W1r = (const float*)d_in[4];
    const float* W2l = (const float*)d_in[5];
    const float* b2  = (const float*)d_in[6];
    const float* W2r = (const float*)d_in[7];
    float* out = (float*)d_out;

    int n = in_sizes[0] / D;       // 50000
    int E = in_sizes[1] / 2;       // 625000
    const int* src = edge;
    const int* dst = edge + E;

    char* w = (char*)d_ws;
    auto alloc = [&](size_t bytes) {
        char* p = w;
        w += (bytes + 255) & ~(size_t)255;
        return p;
    };
    int* cnt      = (int*)alloc((size_t)n * 4);
    int* row_off  = (int*)alloc((size_t)(n + 1) * 4);
    int* cur      = (int*)alloc((size_t)n * 4);
    float* invc   = (float*)alloc((size_t)n * 4);
    int* csr_src  = (int*)alloc((size_t)E * 4);
    float* meanb  = (float*)alloc((size_t)n * D * 4);
    float* hbuf   = (float*)alloc((size_t)n * D * 4);
    int nb = (n + SCAN_B - 1) / SCAN_B;            // 196
    int* blk_sum  = (int*)alloc((size_t)nb * 4);

    hipMemsetAsync(cnt, 0, (size_t)n * 4, stream);
    count_edges<<<(E + 255) / 256, 256, 0, stream>>>(dst, E, cnt);
    scan_part<<<nb, SCAN_B, 0, stream>>>(cnt, n, blk_sum);
    scan_top<<<1, 1024, 0, stream>>>(blk_sum, nb);
    scan_final<<<nb, SCAN_B, 0, stream>>>(cnt, n, blk_sum, row_off, cur, invc);
    fill_csr<<<(E + 255) / 256, 256, 0, stream>>>(src, dst, E, cur, csr_src);

    int gemm_blocks = (n + TN - 1) / TN;
    int agg_blocks = 2048;

    // layer 1
    aggregate<<<agg_blocks, 256, 0, stream>>>(x, csr_src, row_off, invc, meanb, n);
    sage_gemm<1><<<gemm_blocks, 256, 0, stream>>>(meanb, x, W1l, W1r, b1, hbuf, n);
    // layer 2
    aggregate<<<agg_blocks, 256, 0, stream>>>(hbuf, csr_src, row_off, invc, meanb, n);
    sage_gemm<0><<<gemm_blocks, 256, 0, stream>>>(meanb, hbuf, W2l, W2r, b2, out, n);
}

// Round 5
// 198.381 us; speedup vs baseline: 30.2759x; 2.0850x over previous
//
#include <hip/hip_runtime.h>

#define D 128
#define SCAN_B 256

typedef __attribute__((ext_vector_type(8))) short bf16x8;
typedef __attribute__((ext_vector_type(4))) float f32x4v;

__device__ __forceinline__ unsigned short f2b(float f) {
    unsigned int u = __float_as_uint(f);
    unsigned int r = (u + 0x7FFFu + ((u >> 16) & 1u)) >> 16;   // RNE
    return (unsigned short)r;
}
__device__ __forceinline__ float b2f(unsigned short s) {
    return __uint_as_float(((unsigned int)s) << 16);
}

// ---------------- fp32 -> bf16 converts ----------------

__global__ __launch_bounds__(256) void cvt_x(const float* __restrict__ in,
                                             ushort* __restrict__ out, int n4) {
    int i = blockIdx.x * blockDim.x + threadIdx.x;
    if (i >= n4) return;
    float4 v = ((const float4*)in)[i];
    ushort4 o;
    o.x = f2b(v.x); o.y = f2b(v.y); o.z = f2b(v.z); o.w = f2b(v.w);
    ((ushort4*)out)[i] = o;
}

__global__ __launch_bounds__(256) void cvt_w(const float* __restrict__ a, const float* __restrict__ b,
                                             const float* __restrict__ c, const float* __restrict__ d,
                                             ushort* __restrict__ oa, ushort* __restrict__ ob,
                                             ushort* __restrict__ oc, ushort* __restrict__ od) {
    int i = blockIdx.x * blockDim.x + threadIdx.x;   // 0..16383 (4 x 4096 float4)
    int which = i >> 12, j = i & 4095;
    const float* s = which == 0 ? a : which == 1 ? b : which == 2 ? c : d;
    ushort* o = which == 0 ? oa : which == 1 ? ob : which == 2 ? oc : od;
    float4 v = ((const float4*)s)[j];
    ushort4 u;
    u.x = f2b(v.x); u.y = f2b(v.y); u.z = f2b(v.z); u.w = f2b(v.w);
    ((ushort4*)o)[j] = u;
}

// ---------------- CSR build ----------------

__global__ void count_edges(const int* __restrict__ dst, int E, int* __restrict__ cnt) {
    int e = blockIdx.x * blockDim.x + threadIdx.x;
    if (e < E) atomicAdd(&cnt[dst[e]], 1);
}

__global__ void scan_part(const int* __restrict__ cnt, int n, int* __restrict__ blk_sum) {
    __shared__ int s[SCAN_B];
    int i = blockIdx.x * SCAN_B + threadIdx.x;
    s[threadIdx.x] = (i < n) ? cnt[i] : 0;
    __syncthreads();
#pragma unroll
    for (int off = SCAN_B / 2; off > 0; off >>= 1) {
        if (threadIdx.x < off) s[threadIdx.x] += s[threadIdx.x + off];
        __syncthreads();
    }
    if (threadIdx.x == 0) blk_sum[blockIdx.x] = s[0];
}

__global__ void scan_top(int* __restrict__ blk_sum, int nb) {
    __shared__ int s[1024];
    int t = threadIdx.x;
    int v = (t < nb) ? blk_sum[t] : 0;
    s[t] = v;
    __syncthreads();
    for (int off = 1; off < 1024; off <<= 1) {
        int u = (t >= off) ? s[t - off] : 0;
        __syncthreads();
        s[t] += u;
        __syncthreads();
    }
    if (t < nb) blk_sum[t] = s[t] - v;
}

__global__ void scan_final(const int* __restrict__ cnt, int n, const int* __restrict__ blk_sum,
                           int* __restrict__ row_off, int* __restrict__ cur,
                           float* __restrict__ inv_cnt) {
    __shared__ int s[SCAN_B];
    int i = blockIdx.x * SCAN_B + threadIdx.x;
    int v = (i < n) ? cnt[i] : 0;
    s[threadIdx.x] = v;
    __syncthreads();
    for (int off = 1; off < SCAN_B; off <<= 1) {
        int u = (threadIdx.x >= off) ? s[threadIdx.x - off] : 0;
        __syncthreads();
        s[threadIdx.x] += u;
        __syncthreads();
    }
    if (i < n) {
        int excl = blk_sum[blockIdx.x] + s[threadIdx.x] - v;
        row_off[i] = excl;
        cur[i] = excl;
        inv_cnt[i] = 1.0f / (float)max(v, 1);
        if (i == n - 1) row_off[n] = excl + v;
    }
}

__global__ void fill_csr(const int* __restrict__ src, const int* __restrict__ dst, int E,
                         int* __restrict__ cur, int* __restrict__ csr_src) {
    int e = blockIdx.x * blockDim.x + threadIdx.x;
    if (e < E) {
        int d = dst[e];
        int pos = atomicAdd(&cur[d], 1);
        csr_src[pos] = src[e];
    }
}

// ---------------- mean aggregation (bf16 in / bf16 out, fp32 accumulate) -------------
// 2 nodes per wave (one per 32-lane half); each lane gathers bf16x4 (8B); 32x8=256B row.

__global__ __launch_bounds__(256)
void aggregate(const ushort* __restrict__ xb, const int* __restrict__ csr_src,
               const int* __restrict__ row_off, const float* __restrict__ inv_cnt,
               ushort* __restrict__ mean_out, int n) {
    int wave  = (blockIdx.x * blockDim.x + threadIdx.x) >> 6;
    int lane  = threadIdx.x & 63;
    int half  = lane >> 5;
    int l32   = lane & 31;
    int nwave = (gridDim.x * blockDim.x) >> 6;
    for (int p = wave; 2 * p < n; p += nwave) {
        int i = 2 * p + half;
        if (i >= n) continue;
        int lo = row_off[i], hi = row_off[i + 1];
        float a0 = 0.f, a1 = 0.f, a2 = 0.f, a3 = 0.f;
        for (int e = lo; e < hi; ++e) {
            int s = csr_src[e];
            ushort4 v = *(const ushort4*)&xb[(size_t)s * D + l32 * 4];
            a0 += b2f(v.x); a1 += b2f(v.y); a2 += b2f(v.z); a3 += b2f(v.w);
        }
        float ic = inv_cnt[i];
        ushort4 o;
        o.x = f2b(a0 * ic); o.y = f2b(a1 * ic); o.z = f2b(a2 * ic); o.w = f2b(a3 * ic);
        *(ushort4*)&mean_out[(size_t)i * D + l32 * 4] = o;
    }
}

// ---------------- MFMA bf16 GEMM: out = [mean|x] @ [Wl|Wr]^T + b ----------------
// Tile 128 nodes x 128 outs, 4 waves (2x2), wave = 64x64 = 4x4 frags of 16x16x32.
// K = 256 in 8 steps of BK=32; A/B tiles staged via global_load_lds width=16.
// OUT_BF16=1: relu + bf16 store (layer 1). OUT_BF16=0: fp32 store (layer 2).

template <int OUT_BF16>
__global__ __launch_bounds__(256, 2)
void sage_gemm(const ushort* __restrict__ meanb, const ushort* __restrict__ xb,
               const ushort* __restrict__ Wl, const ushort* __restrict__ Wr,
               const float* __restrict__ bias, void* __restrict__ outp, int n) {
    __shared__ ushort As[128 * 32];   // [row][32k], 64B/row
    __shared__ ushort Bs[128 * 32];
    const int tid = threadIdx.x;
    const int node0 = blockIdx.x * 128;
    const int nmax = n - 1;
    const int wid = tid >> 6, l = tid & 63;
    const int wr = wid >> 1, wc = wid & 1;
    const int lrow = l & 15;
    const int lke = (l >> 4) * 8;            // k element offset of frag (8 bf16 = 16B)

    f32x4v acc[4][4] = {};

#pragma unroll 1
    for (int kt = 0; kt < 8; ++kt) {
        const ushort* __restrict__ Asrc = (kt < 4) ? meanb : xb;
        const ushort* __restrict__ Bsrc = (kt < 4) ? Wl : Wr;
        const int ka = (kt & 3) * 32;

        __syncthreads();   // LDS reuse: previous step's reads done
#pragma unroll
        for (int q = 0; q < 2; ++q) {
            int row = q * 64 + (tid >> 2);
            int kelem = ka + (tid & 3) * 8;
            int ldse = q * 2048 + tid * 8;   // element offset (x2 = bytes)
            int node = node0 + row; if (node > nmax) node = nmax;
            __builtin_amdgcn_global_load_lds(
                (const __attribute__((address_space(1))) unsigned int*)(Asrc + (size_t)node * D + kelem),
                (__attribute__((address_space(3))) unsigned int*)&As[ldse], 16, 0, 0);
            __builtin_amdgcn_global_load_lds(
                (const __attribute__((address_space(1))) unsigned int*)(Bsrc + (size_t)row * D + kelem),
                (__attribute__((address_space(3))) unsigned int*)&Bs[ldse], 16, 0, 0);
        }
        __syncthreads();   // drains vmcnt (compiler-inserted) -> tiles ready

        bf16x8 af[4], bf[4];
#pragma unroll
        for (int m = 0; m < 4; ++m)
            af[m] = *(const bf16x8*)&As[(wr * 64 + m * 16 + lrow) * 32 + lke];
#pragma unroll
        for (int nn = 0; nn < 4; ++nn)
            bf[nn] = *(const bf16x8*)&Bs[(wc * 64 + nn * 16 + lrow) * 32 + lke];
#pragma unroll
        for (int m = 0; m < 4; ++m)
#pragma unroll
            for (int nn = 0; nn < 4; ++nn)
                acc[m][nn] = __builtin_amdgcn_mfma_f32_16x16x32_bf16(af[m], bf[nn], acc[m][nn], 0, 0, 0);
    }

    // epilogue: C frag layout col=l&15, row=(l>>4)*4+j
    const int col = l & 15;
    const int r4 = (l >> 4) * 4;
#pragma unroll
    for (int m = 0; m < 4; ++m) {
#pragma unroll
        for (int j = 0; j < 4; ++j) {
            int node = node0 + wr * 64 + m * 16 + r4 + j;
            if (node >= n) continue;
#pragma unroll
            for (int nn = 0; nn < 4; ++nn) {
                int o = wc * 64 + nn * 16 + col;
                float v = acc[m][nn][j] + bias[o];
                if (OUT_BF16) {
                    v = fmaxf(v, 0.f);
                    ((ushort*)outp)[(size_t)node * D + o] = f2b(v);
                } else {
                    ((float*)outp)[(size_t)node * D + o] = v;
                }
            }
        }
    }
}

// ---------------- launch ----------------

extern "C" void kernel_launch(void* const* d_in, const int* in_sizes, int n_in,
                              void* d_out, int out_size, void* d_ws, size_t ws_size,
                              hipStream_t stream) {
    const float* x  = (const float*)d_in[0];
    const int* edge = (const int*)d_in[1];
    const float* W1l = (const float*)d_in[2];
    const float* b1  = (const float*)d_in[3];
    const float* W1r = (const float*)d_in[4];
    const float* W2l = (const float*)d_in[5];
    const float* b2  = (const float*)d_in[6];
    const float* W2r = (const float*)d_in[7];
    float* out = (float*)d_out;

    int n = in_sizes[0] / D;       // 50000
    int E = in_sizes[1] / 2;       // 625000
    const int* src = edge;
    const int* dst = edge + E;

    char* w = (char*)d_ws;
    auto alloc = [&](size_t bytes) {
        char* p = w;
        w += (bytes + 255) & ~(size_t)255;
        return p;
    };
    int* cnt      = (int*)alloc((size_t)n * 4);
    int* row_off  = (int*)alloc((size_t)(n + 1) * 4);
    int* cur      = (int*)alloc((size_t)n * 4);
    float* invc   = (float*)alloc((size_t)n * 4);
    int* csr_src  = (int*)alloc((size_t)E * 4);
    ushort* xb    = (ushort*)alloc((size_t)n * D * 2);
    ushort* meanb = (ushort*)alloc((size_t)n * D * 2);
    ushort* hb    = (ushort*)alloc((size_t)n * D * 2);
    ushort* w1l   = (ushort*)alloc((size_t)D * D * 2);
    ushort* w1r   = (ushort*)alloc((size_t)D * D * 2);
    ushort* w2l   = (ushort*)alloc((size_t)D * D * 2);
    ushort* w2r   = (ushort*)alloc((size_t)D * D * 2);
    int nb = (n + SCAN_B - 1) / SCAN_B;
    int* blk_sum  = (int*)alloc((size_t)nb * 4);

    // converts
    int n4 = n * D / 4;
    cvt_x<<<(n4 + 255) / 256, 256, 0, stream>>>(x, xb, n4);
    cvt_w<<<64, 256, 0, stream>>>(W1l, W1r, W2l, W2r, w1l, w1r, w2l, w2r);

    // CSR build
    hipMemsetAsync(cnt, 0, (size_t)n * 4, stream);
    count_edges<<<(E + 255) / 256, 256, 0, stream>>>(dst, E, cnt);
    scan_part<<<nb, SCAN_B, 0, stream>>>(cnt, n, blk_sum);
    scan_top<<<1, 1024, 0, stream>>>(blk_sum, nb);
    scan_final<<<nb, SCAN_B, 0, stream>>>(cnt, n, blk_sum, row_off, cur, invc);
    fill_csr<<<(E + 255) / 256, 256, 0, stream>>>(src, dst, E, cur, csr_src);

    int gemm_blocks = (n + 127) / 128;
    int agg_blocks = 2048;

    // layer 1
    aggregate<<<agg_blocks, 256, 0, stream>>>(xb, csr_src, row_off, invc, meanb, n);
    sage_gemm<1><<<gemm_blocks, 256, 0, stream>>>(meanb, xb, w1l, w1r, b1, hb, n);
    // layer 2
    aggregate<<<agg_blocks, 256, 0, stream>>>(hb, csr_src, row_off, invc, meanb, n);
    sage_gemm<0><<<gemm_blocks, 256, 0, stream>>>(meanb, hb, w2l, w2r, b2, out, n);
}

// Round 6
// 162.705 us; speedup vs baseline: 36.9144x; 1.2193x over previous
//
#include <hip/hip_runtime.h>

#define D 128
#define SCAN_B 256

typedef __attribute__((ext_vector_type(8))) short bf16x8;
typedef __attribute__((ext_vector_type(4))) float f32x4v;

__device__ __forceinline__ unsigned short f2b(float f) {
    unsigned int u = __float_as_uint(f);
    unsigned int r = (u + 0x7FFFu + ((u >> 16) & 1u)) >> 16;   // RNE
    return (unsigned short)r;
}
__device__ __forceinline__ float b2f(unsigned short s) {
    return __uint_as_float(((unsigned int)s) << 16);
}

// ---------------- fp32 -> bf16 converts ----------------

__global__ __launch_bounds__(256) void cvt_x(const float* __restrict__ in,
                                             ushort* __restrict__ out, int n4) {
    int i = blockIdx.x * blockDim.x + threadIdx.x;
    if (i >= n4) return;
    float4 v = ((const float4*)in)[i];
    ushort4 o;
    o.x = f2b(v.x); o.y = f2b(v.y); o.z = f2b(v.z); o.w = f2b(v.w);
    ((ushort4*)out)[i] = o;
}

__global__ __launch_bounds__(256) void cvt_w(const float* __restrict__ a, const float* __restrict__ b,
                                             const float* __restrict__ c, const float* __restrict__ d,
                                             ushort* __restrict__ oa, ushort* __restrict__ ob,
                                             ushort* __restrict__ oc, ushort* __restrict__ od) {
    int i = blockIdx.x * blockDim.x + threadIdx.x;   // 0..16383 (4 x 4096 float4)
    int which = i >> 12, j = i & 4095;
    const float* s = which == 0 ? a : which == 1 ? b : which == 2 ? c : d;
    ushort* o = which == 0 ? oa : which == 1 ? ob : which == 2 ? oc : od;
    float4 v = ((const float4*)s)[j];
    ushort4 u;
    u.x = f2b(v.x); u.y = f2b(v.y); u.z = f2b(v.z); u.w = f2b(v.w);
    ((ushort4*)o)[j] = u;
}

// ---------------- CSR build ----------------

__global__ void count_edges(const int* __restrict__ dst, int E, int* __restrict__ cnt) {
    int e = blockIdx.x * blockDim.x + threadIdx.x;
    if (e < E) atomicAdd(&cnt[dst[e]], 1);
}

__global__ void scan_part(const int* __restrict__ cnt, int n, int* __restrict__ blk_sum) {
    __shared__ int s[SCAN_B];
    int i = blockIdx.x * SCAN_B + threadIdx.x;
    s[threadIdx.x] = (i < n) ? cnt[i] : 0;
    __syncthreads();
#pragma unroll
    for (int off = SCAN_B / 2; off > 0; off >>= 1) {
        if (threadIdx.x < off) s[threadIdx.x] += s[threadIdx.x + off];
        __syncthreads();
    }
    if (threadIdx.x == 0) blk_sum[blockIdx.x] = s[0];
}

__global__ void scan_top(int* __restrict__ blk_sum, int nb) {
    __shared__ int s[1024];
    int t = threadIdx.x;
    int v = (t < nb) ? blk_sum[t] : 0;
    s[t] = v;
    __syncthreads();
    for (int off = 1; off < 1024; off <<= 1) {
        int u = (t >= off) ? s[t - off] : 0;
        __syncthreads();
        s[t] += u;
        __syncthreads();
    }
    if (t < nb) blk_sum[t] = s[t] - v;
}

__global__ void scan_final(const int* __restrict__ cnt, int n, const int* __restrict__ blk_sum,
                           int* __restrict__ row_off, int* __restrict__ cur,
                           float* __restrict__ inv_cnt) {
    __shared__ int s[SCAN_B];
    int i = blockIdx.x * SCAN_B + threadIdx.x;
    int v = (i < n) ? cnt[i] : 0;
    s[threadIdx.x] = v;
    __syncthreads();
    for (int off = 1; off < SCAN_B; off <<= 1) {
        int u = (threadIdx.x >= off) ? s[threadIdx.x - off] : 0;
        __syncthreads();
        s[threadIdx.x] += u;
        __syncthreads();
    }
    if (i < n) {
        int excl = blk_sum[blockIdx.x] + s[threadIdx.x] - v;
        row_off[i] = excl;
        cur[i] = excl;
        inv_cnt[i] = 1.0f / (float)max(v, 1);
        if (i == n - 1) row_off[n] = excl + v;
    }
}

__global__ void fill_csr(const int* __restrict__ src, const int* __restrict__ dst, int E,
                         int* __restrict__ cur, int* __restrict__ csr_src) {
    int e = blockIdx.x * blockDim.x + threadIdx.x;
    if (e < E) {
        int d = dst[e];
        int pos = atomicAdd(&cur[d], 1);
        csr_src[pos] = src[e];
    }
}

// ---------------- mean aggregation (bf16 in / bf16 out, fp32 accumulate) -------------
// 2 nodes per wave (one per 32-lane half); lane gathers ushort4 (8B); 32x8=256B row.
// Edge loop unrolled x4: 4 independent row-gathers in flight per half-wave.

__global__ __launch_bounds__(256)
void aggregate(const ushort* __restrict__ xb, const int* __restrict__ csr_src,
               const int* __restrict__ row_off, const float* __restrict__ inv_cnt,
               ushort* __restrict__ mean_out, int n) {
    int wave  = (blockIdx.x * blockDim.x + threadIdx.x) >> 6;
    int lane  = threadIdx.x & 63;
    int half  = lane >> 5;
    int l32   = lane & 31;
    int nwave = (gridDim.x * blockDim.x) >> 6;
    for (int p = wave; 2 * p < n; p += nwave) {
        int i = 2 * p + half;
        if (i >= n) continue;
        int lo = row_off[i], hi = row_off[i + 1];
        float ic = inv_cnt[i];
        float p0 = 0.f, p1 = 0.f, p2 = 0.f, p3 = 0.f;   // acc pair A
        float q0 = 0.f, q1 = 0.f, q2 = 0.f, q3 = 0.f;   // acc pair B
        int e = lo;
        for (; e + 4 <= hi; e += 4) {
            int s0 = csr_src[e + 0];
            int s1 = csr_src[e + 1];
            int s2 = csr_src[e + 2];
            int s3 = csr_src[e + 3];
            ushort4 v0 = *(const ushort4*)&xb[(size_t)s0 * D + l32 * 4];
            ushort4 v1 = *(const ushort4*)&xb[(size_t)s1 * D + l32 * 4];
            ushort4 v2 = *(const ushort4*)&xb[(size_t)s2 * D + l32 * 4];
            ushort4 v3 = *(const ushort4*)&xb[(size_t)s3 * D + l32 * 4];
            p0 += b2f(v0.x); p1 += b2f(v0.y); p2 += b2f(v0.z); p3 += b2f(v0.w);
            q0 += b2f(v1.x); q1 += b2f(v1.y); q2 += b2f(v1.z); q3 += b2f(v1.w);
            p0 += b2f(v2.x); p1 += b2f(v2.y); p2 += b2f(v2.z); p3 += b2f(v2.w);
            q0 += b2f(v3.x); q1 += b2f(v3.y); q2 += b2f(v3.z); q3 += b2f(v3.w);
        }
        for (; e < hi; ++e) {
            int s = csr_src[e];
            ushort4 v = *(const ushort4*)&xb[(size_t)s * D + l32 * 4];
            p0 += b2f(v.x); p1 += b2f(v.y); p2 += b2f(v.z); p3 += b2f(v.w);
        }
        ushort4 o;
        o.x = f2b((p0 + q0) * ic); o.y = f2b((p1 + q1) * ic);
        o.z = f2b((p2 + q2) * ic); o.w = f2b((p3 + q3) * ic);
        *(ushort4*)&mean_out[(size_t)i * D + l32 * 4] = o;
    }
}

// ---------------- MFMA bf16 GEMM: out = [mean|x] @ [Wl|Wr]^T + b ----------------
// Tile 128 nodes x 128 outs, 4 waves (2x2), wave = 64x64 = 4x4 frags of 16x16x32.
// K = 256 in 8 steps of BK=32; A/B tiles staged via global_load_lds width=16.

template <int OUT_BF16>
__global__ __launch_bounds__(256, 2)
void sage_gemm(const ushort* __restrict__ meanb, const ushort* __restrict__ xb,
               const ushort* __restrict__ Wl, const ushort* __restrict__ Wr,
               const float* __restrict__ bias, void* __restrict__ outp, int n) {
    __shared__ ushort As[128 * 32];   // [row][32k], 64B/row
    __shared__ ushort Bs[128 * 32];
    const int tid = threadIdx.x;
    const int node0 = blockIdx.x * 128;
    const int nmax = n - 1;
    const int wid = tid >> 6, l = tid & 63;
    const int wr = wid >> 1, wc = wid & 1;
    const int lrow = l & 15;
    const int lke = (l >> 4) * 8;            // k element offset of frag (8 bf16 = 16B)

    f32x4v acc[4][4] = {};

#pragma unroll 1
    for (int kt = 0; kt < 8; ++kt) {
        const ushort* __restrict__ Asrc = (kt < 4) ? meanb : xb;
        const ushort* __restrict__ Bsrc = (kt < 4) ? Wl : Wr;
        const int ka = (kt & 3) * 32;

        __syncthreads();   // LDS reuse: previous step's reads done
#pragma unroll
        for (int q = 0; q < 2; ++q) {
            int row = q * 64 + (tid >> 2);
            int kelem = ka + (tid & 3) * 8;
            int ldse = q * 2048 + tid * 8;   // element offset (x2 = bytes)
            int node = node0 + row; if (node > nmax) node = nmax;
            __builtin_amdgcn_global_load_lds(
                (const __attribute__((address_space(1))) unsigned int*)(Asrc + (size_t)node * D + kelem),
                (__attribute__((address_space(3))) unsigned int*)&As[ldse], 16, 0, 0);
            __builtin_amdgcn_global_load_lds(
                (const __attribute__((address_space(1))) unsigned int*)(Bsrc + (size_t)row * D + kelem),
                (__attribute__((address_space(3))) unsigned int*)&Bs[ldse], 16, 0, 0);
        }
        __syncthreads();   // drains vmcnt -> tiles ready

        bf16x8 af[4], bf[4];
#pragma unroll
        for (int m = 0; m < 4; ++m)
            af[m] = *(const bf16x8*)&As[(wr * 64 + m * 16 + lrow) * 32 + lke];
#pragma unroll
        for (int nn = 0; nn < 4; ++nn)
            bf[nn] = *(const bf16x8*)&Bs[(wc * 64 + nn * 16 + lrow) * 32 + lke];
#pragma unroll
        for (int m = 0; m < 4; ++m)
#pragma unroll
            for (int nn = 0; nn < 4; ++nn)
                acc[m][nn] = __builtin_amdgcn_mfma_f32_16x16x32_bf16(af[m], bf[nn], acc[m][nn], 0, 0, 0);
    }

    // epilogue: C frag layout col=l&15, row=(l>>4)*4+j
    const int col = l & 15;
    const int r4 = (l >> 4) * 4;
#pragma unroll
    for (int m = 0; m < 4; ++m) {
#pragma unroll
        for (int j = 0; j < 4; ++j) {
            int node = node0 + wr * 64 + m * 16 + r4 + j;
            if (node >= n) continue;
#pragma unroll
            for (int nn = 0; nn < 4; ++nn) {
                int o = wc * 64 + nn * 16 + col;
                float v = acc[m][nn][j] + bias[o];
                if (OUT_BF16) {
                    v = fmaxf(v, 0.f);
                    ((ushort*)outp)[(size_t)node * D + o] = f2b(v);
                } else {
                    ((float*)outp)[(size_t)node * D + o] = v;
                }
            }
        }
    }
}

// ---------------- launch ----------------

extern "C" void kernel_launch(void* const* d_in, const int* in_sizes, int n_in,
                              void* d_out, int out_size, void* d_ws, size_t ws_size,
                              hipStream_t stream) {
    const float* x  = (const float*)d_in[0];
    const int* edge = (const int*)d_in[1];
    const float* W1l = (const float*)d_in[2];
    const float* b1  = (const float*)d_in[3];
    const float* W1r = (const float*)d_in[4];
    const float* W2l = (const float*)d_in[5];
    const float* b2  = (const float*)d_in[6];
    const float* W2r = (const float*)d_in[7];
    float* out = (float*)d_out;

    int n = in_sizes[0] / D;       // 50000
    int E = in_sizes[1] / 2;       // 625000
    const int* src = edge;
    const int* dst = edge + E;

    char* w = (char*)d_ws;
    auto alloc = [&](size_t bytes) {
        char* p = w;
        w += (bytes + 255) & ~(size_t)255;
        return p;
    };
    int* cnt      = (int*)alloc((size_t)n * 4);
    int* row_off  = (int*)alloc((size_t)(n + 1) * 4);
    int* cur      = (int*)alloc((size_t)n * 4);
    float* invc   = (float*)alloc((size_t)n * 4);
    int* csr_src  = (int*)alloc((size_t)E * 4);
    ushort* xb    = (ushort*)alloc((size_t)n * D * 2);
    ushort* meanb = (ushort*)alloc((size_t)n * D * 2);
    ushort* hb    = (ushort*)alloc((size_t)n * D * 2);
    ushort* w1l   = (ushort*)alloc((size_t)D * D * 2);
    ushort* w1r   = (ushort*)alloc((size_t)D * D * 2);
    ushort* w2l   = (ushort*)alloc((size_t)D * D * 2);
    ushort* w2r   = (ushort*)alloc((size_t)D * D * 2);
    int nb = (n + SCAN_B - 1) / SCAN_B;
    int* blk_sum  = (int*)alloc((size_t)nb * 4);

    // converts
    int n4 = n * D / 4;
    cvt_x<<<(n4 + 255) / 256, 256, 0, stream>>>(x, xb, n4);
    cvt_w<<<64, 256, 0, stream>>>(W1l, W1r, W2l, W2r, w1l, w1r, w2l, w2r);

    // CSR build
    hipMemsetAsync(cnt, 0, (size_t)n * 4, stream);
    count_edges<<<(E + 255) / 256, 256, 0, stream>>>(dst, E, cnt);
    scan_part<<<nb, SCAN_B, 0, stream>>>(cnt, n, blk_sum);
    scan_top<<<1, 1024, 0, stream>>>(blk_sum, nb);
    scan_final<<<nb, SCAN_B, 0, stream>>>(cnt, n, blk_sum, row_off, cur, invc);
    fill_csr<<<(E + 255) / 256, 256, 0, stream>>>(src, dst, E, cur, csr_src);

    int gemm_blocks = (n + 127) / 128;
    int agg_blocks = 2048;

    // layer 1
    aggregate<<<agg_blocks, 256, 0, stream>>>(xb, csr_src, row_off, invc, meanb, n);
    sage_gemm<1><<<gemm_blocks, 256, 0, stream>>>(meanb, xb, w1l, w1r, b1, hb, n);
    // layer 2
    aggregate<<<agg_blocks, 256, 0, stream>>>(hb, csr_src, row_off, invc, meanb, n);
    sage_gemm<0><<<gemm_blocks, 256, 0, stream>>>(meanb, hb, w2l, w2r, b2, out, n);
}

// Round 7
// 155.784 us; speedup vs baseline: 38.5545x; 1.0444x over previous
//
#include <hip/hip_runtime.h>

#define D 128
#define SCAN_B 256

typedef __attribute__((ext_vector_type(8))) short bf16x8;
typedef __attribute__((ext_vector_type(4))) float f32x4v;
typedef __attribute__((ext_vector_type(8))) unsigned short ushort8v;

__device__ __forceinline__ unsigned short f2b(float f) {
    unsigned int u = __float_as_uint(f);
    unsigned int r = (u + 0x7FFFu + ((u >> 16) & 1u)) >> 16;   // RNE
    return (unsigned short)r;
}
__device__ __forceinline__ float b2f(unsigned short s) {
    return __uint_as_float(((unsigned int)s) << 16);
}

// ---------------- fp32 -> bf16 converts ----------------

__global__ __launch_bounds__(256) void cvt_x(const float* __restrict__ in,
                                             ushort* __restrict__ out, int n4) {
    int i = blockIdx.x * blockDim.x + threadIdx.x;
    if (i >= n4) return;
    float4 v = ((const float4*)in)[i];
    ushort4 o;
    o.x = f2b(v.x); o.y = f2b(v.y); o.z = f2b(v.z); o.w = f2b(v.w);
    ((ushort4*)out)[i] = o;
}

__global__ __launch_bounds__(256) void cvt_w(const float* __restrict__ a, const float* __restrict__ b,
                                             const float* __restrict__ c, const float* __restrict__ d,
                                             ushort* __restrict__ oa, ushort* __restrict__ ob,
                                             ushort* __restrict__ oc, ushort* __restrict__ od) {
    int i = blockIdx.x * blockDim.x + threadIdx.x;   // 0..16383 (4 x 4096 float4)
    int which = i >> 12, j = i & 4095;
    const float* s = which == 0 ? a : which == 1 ? b : which == 2 ? c : d;
    ushort* o = which == 0 ? oa : which == 1 ? ob : which == 2 ? oc : od;
    float4 v = ((const float4*)s)[j];
    ushort4 u;
    u.x = f2b(v.x); u.y = f2b(v.y); u.z = f2b(v.z); u.w = f2b(v.w);
    ((ushort4*)o)[j] = u;
}

// ---------------- CSR build ----------------

__global__ __launch_bounds__(256) void zero_cnt(int* __restrict__ cnt, int n) {
    int i = blockIdx.x * blockDim.x + threadIdx.x;
    if (i < n) cnt[i] = 0;
}

__global__ void count_edges(const int* __restrict__ dst, int E, int* __restrict__ cnt) {
    int e = blockIdx.x * blockDim.x + threadIdx.x;
    if (e < E) atomicAdd(&cnt[dst[e]], 1);
}

__global__ void scan_part(const int* __restrict__ cnt, int n, int* __restrict__ blk_sum) {
    __shared__ int s[SCAN_B];
    int i = blockIdx.x * SCAN_B + threadIdx.x;
    s[threadIdx.x] = (i < n) ? cnt[i] : 0;
    __syncthreads();
#pragma unroll
    for (int off = SCAN_B / 2; off > 0; off >>= 1) {
        if (threadIdx.x < off) s[threadIdx.x] += s[threadIdx.x + off];
        __syncthreads();
    }
    if (threadIdx.x == 0) blk_sum[blockIdx.x] = s[0];
}

__global__ void scan_top(int* __restrict__ blk_sum, int nb) {
    __shared__ int s[1024];
    int t = threadIdx.x;
    int v = (t < nb) ? blk_sum[t] : 0;
    s[t] = v;
    __syncthreads();
    for (int off = 1; off < 1024; off <<= 1) {
        int u = (t >= off) ? s[t - off] : 0;
        __syncthreads();
        s[t] += u;
        __syncthreads();
    }
    if (t < nb) blk_sum[t] = s[t] - v;
}

__global__ void scan_final(const int* __restrict__ cnt, int n, const int* __restrict__ blk_sum,
                           int* __restrict__ row_off, int* __restrict__ cur,
                           float* __restrict__ inv_cnt) {
    __shared__ int s[SCAN_B];
    int i = blockIdx.x * SCAN_B + threadIdx.x;
    int v = (i < n) ? cnt[i] : 0;
    s[threadIdx.x] = v;
    __syncthreads();
    for (int off = 1; off < SCAN_B; off <<= 1) {
        int u = (threadIdx.x >= off) ? s[threadIdx.x - off] : 0;
        __syncthreads();
        s[threadIdx.x] += u;
        __syncthreads();
    }
    if (i < n) {
        int excl = blk_sum[blockIdx.x] + s[threadIdx.x] - v;
        row_off[i] = excl;
        cur[i] = excl;
        inv_cnt[i] = 1.0f / (float)max(v, 1);
        if (i == n - 1) row_off[n] = excl + v;
    }
}

__global__ void fill_csr(const int* __restrict__ src, const int* __restrict__ dst, int E,
                         int* __restrict__ cur, int* __restrict__ csr_src) {
    int e = blockIdx.x * blockDim.x + threadIdx.x;
    if (e < E) {
        int d = dst[e];
        int pos = atomicAdd(&cur[d], 1);
        csr_src[pos] = src[e];
    }
}

// ---------------- mean aggregation (bf16 in / bf16 out, fp32 accumulate) -------------
// 4 nodes per wave (16 lanes each); lane gathers ushort8 (16B); 16x16=256B per row.
// Edge loop unrolled x4: up to 16 distinct rows in flight per wave.

__global__ __launch_bounds__(256)
void aggregate(const ushort* __restrict__ xb, const int* __restrict__ csr_src,
               const int* __restrict__ row_off, const float* __restrict__ inv_cnt,
               ushort* __restrict__ mean_out, int n) {
    int wave  = (blockIdx.x * blockDim.x + threadIdx.x) >> 6;
    int lane  = threadIdx.x & 63;
    int quad  = lane >> 4;        // 0..3: node within group
    int l16   = lane & 15;        // 0..15: channel chunk
    int nwave = (gridDim.x * blockDim.x) >> 6;
    for (int p = wave; 4 * p < n; p += nwave) {
        int i = 4 * p + quad;
        if (i >= n) continue;
        int lo = row_off[i], hi = row_off[i + 1];
        float ic = inv_cnt[i];
        float a0 = 0.f, a1 = 0.f, a2 = 0.f, a3 = 0.f, a4 = 0.f, a5 = 0.f, a6 = 0.f, a7 = 0.f;
        float b0 = 0.f, b1 = 0.f, b2 = 0.f, b3 = 0.f, b4 = 0.f, b5 = 0.f, b6 = 0.f, b7 = 0.f;
        int e = lo;
        for (; e + 4 <= hi; e += 4) {
            int s0 = csr_src[e + 0];
            int s1 = csr_src[e + 1];
            int s2 = csr_src[e + 2];
            int s3 = csr_src[e + 3];
            ushort8v v0 = *(const ushort8v*)&xb[(size_t)s0 * D + l16 * 8];
            ushort8v v1 = *(const ushort8v*)&xb[(size_t)s1 * D + l16 * 8];
            ushort8v v2 = *(const ushort8v*)&xb[(size_t)s2 * D + l16 * 8];
            ushort8v v3 = *(const ushort8v*)&xb[(size_t)s3 * D + l16 * 8];
            a0 += b2f(v0[0]); a1 += b2f(v0[1]); a2 += b2f(v0[2]); a3 += b2f(v0[3]);
            a4 += b2f(v0[4]); a5 += b2f(v0[5]); a6 += b2f(v0[6]); a7 += b2f(v0[7]);
            b0 += b2f(v1[0]); b1 += b2f(v1[1]); b2 += b2f(v1[2]); b3 += b2f(v1[3]);
            b4 += b2f(v1[4]); b5 += b2f(v1[5]); b6 += b2f(v1[6]); b7 += b2f(v1[7]);
            a0 += b2f(v2[0]); a1 += b2f(v2[1]); a2 += b2f(v2[2]); a3 += b2f(v2[3]);
            a4 += b2f(v2[4]); a5 += b2f(v2[5]); a6 += b2f(v2[6]); a7 += b2f(v2[7]);
            b0 += b2f(v3[0]); b1 += b2f(v3[1]); b2 += b2f(v3[2]); b3 += b2f(v3[3]);
            b4 += b2f(v3[4]); b5 += b2f(v3[5]); b6 += b2f(v3[6]); b7 += b2f(v3[7]);
        }
        for (; e < hi; ++e) {
            int s = csr_src[e];
            ushort8v v = *(const ushort8v*)&xb[(size_t)s * D + l16 * 8];
            a0 += b2f(v[0]); a1 += b2f(v[1]); a2 += b2f(v[2]); a3 += b2f(v[3]);
            a4 += b2f(v[4]); a5 += b2f(v[5]); a6 += b2f(v[6]); a7 += b2f(v[7]);
        }
        ushort8v o;
        o[0] = f2b((a0 + b0) * ic); o[1] = f2b((a1 + b1) * ic);
        o[2] = f2b((a2 + b2) * ic); o[3] = f2b((a3 + b3) * ic);
        o[4] = f2b((a4 + b4) * ic); o[5] = f2b((a5 + b5) * ic);
        o[6] = f2b((a6 + b6) * ic); o[7] = f2b((a7 + b7) * ic);
        *(ushort8v*)&mean_out[(size_t)i * D + l16 * 8] = o;
    }
}

// ---------------- MFMA bf16 GEMM: out = [mean|x] @ [Wl|Wr]^T + b ----------------
// Tile 128 nodes x 128 outs, 4 waves (2x2), wave = 64x64 = 4x4 frags of 16x16x32.
// K = 256 in 8 steps of BK=32; A/B tiles staged via global_load_lds width=16.

template <int OUT_BF16>
__global__ __launch_bounds__(256, 2)
void sage_gemm(const ushort* __restrict__ meanb, const ushort* __restrict__ xb,
               const ushort* __restrict__ Wl, const ushort* __restrict__ Wr,
               const float* __restrict__ bias, void* __restrict__ outp, int n) {
    __shared__ ushort As[128 * 32];   // [row][32k], 64B/row
    __shared__ ushort Bs[128 * 32];
    const int tid = threadIdx.x;
    const int node0 = blockIdx.x * 128;
    const int nmax = n - 1;
    const int wid = tid >> 6, l = tid & 63;
    const int wr = wid >> 1, wc = wid & 1;
    const int lrow = l & 15;
    const int lke = (l >> 4) * 8;            // k element offset of frag (8 bf16 = 16B)

    f32x4v acc[4][4] = {};

#pragma unroll 1
    for (int kt = 0; kt < 8; ++kt) {
        const ushort* __restrict__ Asrc = (kt < 4) ? meanb : xb;
        const ushort* __restrict__ Bsrc = (kt < 4) ? Wl : Wr;
        const int ka = (kt & 3) * 32;

        __syncthreads();   // LDS reuse: previous step's reads done
#pragma unroll
        for (int q = 0; q < 2; ++q) {
            int row = q * 64 + (tid >> 2);
            int kelem = ka + (tid & 3) * 8;
            int ldse = q * 2048 + tid * 8;   // element offset (x2 = bytes)
            int node = node0 + row; if (node > nmax) node = nmax;
            __builtin_amdgcn_global_load_lds(
                (const __attribute__((address_space(1))) unsigned int*)(Asrc + (size_t)node * D + kelem),
                (__attribute__((address_space(3))) unsigned int*)&As[ldse], 16, 0, 0);
            __builtin_amdgcn_global_load_lds(
                (const __attribute__((address_space(1))) unsigned int*)(Bsrc + (size_t)row * D + kelem),
                (__attribute__((address_space(3))) unsigned int*)&Bs[ldse], 16, 0, 0);
        }
        __syncthreads();   // drains vmcnt -> tiles ready

        bf16x8 af[4], bf[4];
#pragma unroll
        for (int m = 0; m < 4; ++m)
            af[m] = *(const bf16x8*)&As[(wr * 64 + m * 16 + lrow) * 32 + lke];
#pragma unroll
        for (int nn = 0; nn < 4; ++nn)
            bf[nn] = *(const bf16x8*)&Bs[(wc * 64 + nn * 16 + lrow) * 32 + lke];
#pragma unroll
        for (int m = 0; m < 4; ++m)
#pragma unroll
            for (int nn = 0; nn < 4; ++nn)
                acc[m][nn] = __builtin_amdgcn_mfma_f32_16x16x32_bf16(af[m], bf[nn], acc[m][nn], 0, 0, 0);
    }

    // epilogue: C frag layout col=l&15, row=(l>>4)*4+j
    const int col = l & 15;
    const int r4 = (l >> 4) * 4;
#pragma unroll
    for (int m = 0; m < 4; ++m) {
#pragma unroll
        for (int j = 0; j < 4; ++j) {
            int node = node0 + wr * 64 + m * 16 + r4 + j;
            if (node >= n) continue;
#pragma unroll
            for (int nn = 0; nn < 4; ++nn) {
                int o = wc * 64 + nn * 16 + col;
                float v = acc[m][nn][j] + bias[o];
                if (OUT_BF16) {
                    v = fmaxf(v, 0.f);
                    ((ushort*)outp)[(size_t)node * D + o] = f2b(v);
                } else {
                    ((float*)outp)[(size_t)node * D + o] = v;
                }
            }
        }
    }
}

// ---------------- launch ----------------

extern "C" void kernel_launch(void* const* d_in, const int* in_sizes, int n_in,
                              void* d_out, int out_size, void* d_ws, size_t ws_size,
                              hipStream_t stream) {
    const float* x  = (const float*)d_in[0];
    const int* edge = (const int*)d_in[1];
    const float* W1l = (const float*)d_in[2];
    const float* b1  = (const float*)d_in[3];
    const float* W1r = (const float*)d_in[4];
    const float* W2l = (const float*)d_in[5];
    const float* b2  = (const float*)d_in[6];
    const float* W2r = (const float*)d_in[7];
    float* out = (float*)d_out;

    int n = in_sizes[0] / D;       // 50000
    int E = in_sizes[1] / 2;       // 625000
    const int* src = edge;
    const int* dst = edge + E;

    char* w = (char*)d_ws;
    auto alloc = [&](size_t bytes) {
        char* p = w;
        w += (bytes + 255) & ~(size_t)255;
        return p;
    };
    int* cnt      = (int*)alloc((size_t)n * 4);
    int* row_off  = (int*)alloc((size_t)(n + 1) * 4);
    int* cur      = (int*)alloc((size_t)n * 4);
    float* invc   = (float*)alloc((size_t)n * 4);
    int* csr_src  = (int*)alloc((size_t)E * 4);
    ushort* xb    = (ushort*)alloc((size_t)n * D * 2);
    ushort* meanb = (ushort*)alloc((size_t)n * D * 2);
    ushort* hb    = (ushort*)alloc((size_t)n * D * 2);
    ushort* w1l   = (ushort*)alloc((size_t)D * D * 2);
    ushort* w1r   = (ushort*)alloc((size_t)D * D * 2);
    ushort* w2l   = (ushort*)alloc((size_t)D * D * 2);
    ushort* w2r   = (ushort*)alloc((size_t)D * D * 2);
    int nb = (n + SCAN_B - 1) / SCAN_B;
    int* blk_sum  = (int*)alloc((size_t)nb * 4);

    // converts
    int n4 = n * D / 4;
    cvt_x<<<(n4 + 255) / 256, 256, 0, stream>>>(x, xb, n4);
    cvt_w<<<64, 256, 0, stream>>>(W1l, W1r, W2l, W2r, w1l, w1r, w2l, w2r);

    // CSR build (zero_cnt kernel instead of hipMemsetAsync -> no fillBufferAligned in graph)
    zero_cnt<<<(n + 255) / 256, 256, 0, stream>>>(cnt, n);
    count_edges<<<(E + 255) / 256, 256, 0, stream>>>(dst, E, cnt);
    scan_part<<<nb, SCAN_B, 0, stream>>>(cnt, n, blk_sum);
    scan_top<<<1, 1024, 0, stream>>>(blk_sum, nb);
    scan_final<<<nb, SCAN_B, 0, stream>>>(cnt, n, blk_sum, row_off, cur, invc);
    fill_csr<<<(E + 255) / 256, 256, 0, stream>>>(src, dst, E, cur, csr_src);

    int gemm_blocks = (n + 127) / 128;
    int agg_blocks = 2048;

    // layer 1
    aggregate<<<agg_blocks, 256, 0, stream>>>(xb, csr_src, row_off, invc, meanb, n);
    sage_gemm<1><<<gemm_blocks, 256, 0, stream>>>(meanb, xb, w1l, w1r, b1, hb, n);
    // layer 2
    aggregate<<<agg_blocks, 256, 0, stream>>>(hb, csr_src, row_off, invc, meanb, n);
    sage_gemm<0><<<gemm_blocks, 256, 0, stream>>>(meanb, hb, w2l, w2r, b2, out, n);
}